// Round 15
// baseline (103.307 us; speedup 1.0000x reference)
//
#include <hip/hip_runtime.h>

// ReceptiveFieldNorm, N=16 C=3 H=W=768, fp32. Two iterations (win 51 then 13
// at 256x256). All vertical boxes are horizontal shfl-scans in transposed
// orientation. 6 dispatches. This revision: k_final processes one y-triple
// (3d,3d+1,3d+2) per 768-thread block, scan-free: 3 shared map rows loaded
// once (12KB vs 24KB), packed float4 ry rows, 2 barriers.

#define N_B 16
#define CCH 3
#define HF 768
#define HL 256
#define SLICE (HL * HL)
#define TOT_L (N_B * SLICE)
#define EPSV 1e-3f

__device__ __forceinline__ int cnt(int i, int P) {
  int hi = i + P; if (hi > HL - 1) hi = HL - 1;
  int lo = i - P; if (lo < 0) lo = 0;
  return hi - lo + 1;
}

// Dual inclusive prefix scan of a 256-wide row per group g into s[g][*].
// 2 syncthreads. Caller must pass a FRESH buffer pair (s,wt) per call.
template <int G>
__device__ __forceinline__ void scan2g(float a, float b, int g, int j,
    float2 (*s)[HL], float2 (*wt)[4]) {
  int lane = j & 63, w = j >> 6;
#pragma unroll
  for (int d = 1; d < 64; d <<= 1) {
    float ta = __shfl_up(a, (unsigned)d);
    float tb = __shfl_up(b, (unsigned)d);
    if (lane >= d) { a += ta; b += tb; }
  }
  if (lane == 63) wt[g][w] = make_float2(a, b);
  __syncthreads();
  float offa = 0.f, offb = 0.f;
  for (int ww = 0; ww < w; ++ww) { float2 t = wt[g][ww]; offa += t.x; offb += t.y; }
  s[g][j] = make_float2(a + offa, b + offb);
  __syncthreads();
}

// Zero-padded box result at position j from prefix array s[g].
template <int P>
__device__ __forceinline__ float2 boxr(const float2 (*s)[HL], int g, int j) {
  int hi = j + P; if (hi > HL - 1) hi = HL - 1;
  int lo = j - P - 1;
  float2 r = s[g][hi];
  if (lo >= 0) { float2 l = s[g][lo]; r.x -= l.x; r.y -= l.y; }
  return r;
}

// Transposed write: threads tid<512 each write one float4 (2 packed float2).
template <int P>
__device__ __forceinline__ void xpose_store(const float2 (*s)[HL], int tid,
    float2* __restrict__ dst, size_t nb, int col0) {
  if (tid < 512) {
    int row = tid & 255, half = tid >> 8;
    float2 r0 = boxr<P>(s, 2 * half, row);
    float2 r1 = boxr<P>(s, 2 * half + 1, row);
    float4* d = (float4*)(dst + nb + (size_t)row * HL + col0);
    d[half] = make_float4(r0.x, r0.y, r1.x, r1.y);
  }
}

// ---------- k1: subsample + channel stats -> UV [N]; H25 scan -> S [T]
__global__ __launch_bounds__(1024) void k1(const float* __restrict__ x,
    float2* __restrict__ UV, float2* __restrict__ Spk) {
  __shared__ float2 sA[4][HL];
  __shared__ float2 wtA[4][4];
  int b = blockIdx.x;
  int n = b >> 6;           // 64 blocks per image
  int ib = (b & 63) << 2;   // first of 4 subsample rows
  int tid = threadIdx.x;
  int g = tid >> 8, j = tid & 255;
  const float* xp = x + (size_t)n * CCH * HF * HF
                  + (size_t)(3 * (ib + g) + 1) * HF + (3 * j + 1);
  float c0 = xp[0], c1 = xp[HF * HF], c2 = xp[2 * HF * HF];
  float uu = (c0 + c1 + c2) * (1.f / 3.f);
  float vv = (c0 * c0 + c1 * c1 + c2 * c2) * (1.f / 3.f);
  size_t nb = (size_t)n * SLICE;
  UV[nb + (size_t)(ib + g) * HL + j] = make_float2(uu, vv);
  scan2g<4>(uu, vv, g, j, sA, wtA);
  xpose_store<25>(sA, tid, Spk, nb, ib);  // S[col=j][row=ib+g]
}

// ---------- k2: [T] scan25 -> box(u,v) -> f -> scan25 -> P [N]
__global__ __launch_bounds__(1024) void k2(const float2* __restrict__ Spk,
    float2* __restrict__ Ppk) {
  __shared__ float2 sA[4][HL], sB[4][HL];
  __shared__ float2 wtA[4][4], wtB[4][4];
  int n = blockIdx.x >> 6, strip = blockIdx.x & 63;
  int tid = threadIdx.x, g = tid >> 8, j = tid & 255;
  int c = strip * 4 + g;  // image col (T-row)
  size_t nb = (size_t)n * SLICE;
  float2 sv = Spk[nb + (size_t)c * HL + j];
  scan2g<4>(sv.x, sv.y, g, j, sA, wtA);   // V25 prefix
  float2 bu = boxr<25>(sA, g, j);         // full box25 at (row j, col c)
  float invM = 1.f / ((float)cnt(j, 25) * (float)cnt(c, 25));
  float xm = bu.x * invM, x2m = bu.y * invM;
  float var = x2m - xm * xm; if (var < 0.f) var = 0.f;
  float inv = 1.f / sqrtf(var + EPSV);
  scan2g<4>(inv, -xm * inv, g, j, sB, wtB);  // V25 prefix of (a,b)
  xpose_store<25>(sB, tid, Ppk, nb, strip * 4);  // P[row=j][col=c]
}

// ---------- k3: [N] scan25 -> A1,B1; iter2 stats; H6 scan -> Q [T]
__global__ __launch_bounds__(1024) void k3(const float2* __restrict__ Ppk,
    const float2* __restrict__ UV, float2* __restrict__ AB1,
    float2* __restrict__ Qpk) {
  __shared__ float2 sA[4][HL], sB[4][HL];
  __shared__ float2 wtA[4][4], wtB[4][4];
  int n = blockIdx.x >> 6, strip = blockIdx.x & 63;
  int tid = threadIdx.x, g = tid >> 8, j = tid & 255;
  int i = strip * 4 + g;  // image row
  size_t nb = (size_t)n * SLICE;
  size_t idx = nb + (size_t)i * HL + j;
  float2 pv = Ppk[idx];
  scan2g<4>(pv.x, pv.y, g, j, sA, wtA);   // H25 prefix of (a,b)
  float2 bb = boxr<25>(sA, g, j);
  float invM = 1.f / ((float)cnt(i, 25) * (float)cnt(j, 25));
  float Av = bb.x * invM, Bv = bb.y * invM;
  AB1[idx] = make_float2(Av, Bv);
  float2 uv = UV[idx];
  float u2 = Av * uv.x + Bv;
  float v2 = Av * Av * uv.y + 2.f * Av * Bv * uv.x + Bv * Bv;
  scan2g<4>(u2, v2, g, j, sB, wtB);       // H6 prefix of (u2,v2)
  xpose_store<6>(sB, tid, Qpk, nb, strip * 4);  // Q[col=j][row=i]
}

// ---------- k4: [T] scan6 -> box6 -> f6 -> scan6 -> R [N]
__global__ __launch_bounds__(1024) void k4(const float2* __restrict__ Qpk,
    float2* __restrict__ Rpk) {
  __shared__ float2 sA[4][HL], sB[4][HL];
  __shared__ float2 wtA[4][4], wtB[4][4];
  int n = blockIdx.x >> 6, strip = blockIdx.x & 63;
  int tid = threadIdx.x, g = tid >> 8, j = tid & 255;
  int c = strip * 4 + g;  // image col
  size_t nb = (size_t)n * SLICE;
  float2 qv = Qpk[nb + (size_t)c * HL + j];
  scan2g<4>(qv.x, qv.y, g, j, sA, wtA);   // V6 prefix
  float2 bu = boxr<6>(sA, g, j);          // full box6 at (row j, col c)
  float invM = 1.f / ((float)cnt(j, 6) * (float)cnt(c, 6));
  float xm = bu.x * invM, x2m = bu.y * invM;
  float var = x2m - xm * xm; if (var < 0.f) var = 0.f;
  float inv = 1.f / sqrtf(var + EPSV);
  scan2g<4>(inv, -xm * inv, g, j, sB, wtB);  // V6 prefix of (a2,b2)
  xpose_store<6>(sB, tid, Rpk, nb, strip * 4);  // R[row=j][col=c]
}

// ---------- k5: [N] H6 scan of R -> normalized AB2 maps (direct write)
__global__ __launch_bounds__(1024) void k5(const float2* __restrict__ Rpk,
    float2* __restrict__ AB2) {
  __shared__ float2 sA[4][HL];
  __shared__ float2 wtA[4][4];
  int n = blockIdx.x >> 6, strip = blockIdx.x & 63;
  int tid = threadIdx.x, g = tid >> 8, j = tid & 255;
  int i = strip * 4 + g;  // image row
  size_t nb = (size_t)n * SLICE;
  size_t idx = nb + (size_t)i * HL + j;
  float2 rv = Rpk[idx];
  scan2g<4>(rv.x, rv.y, g, j, sA, wtA);   // H6 prefix
  float2 bb = boxr<6>(sA, g, j);
  float invM = 1.f / ((float)cnt(i, 6) * (float)cnt(j, 6));
  AB2[idx] = make_float2(bb.x * invM, bb.y * invM);
}

// ---------- bilinear upsample weights for 256 -> 768 (period-3 pattern)
__device__ __forceinline__ void upw(int q, int& i0, int& i1, float& w1) {
  int d = q / 3;
  int r = q - 3 * d;
  if (r == 1) { i0 = d; i1 = d; w1 = 0.f; }
  else if (r == 2) { i0 = d; i1 = d + 1; if (i1 > HL - 1) i1 = HL - 1; w1 = 1.f / 3.f; }
  else { i1 = d; i0 = d - 1; if (i0 < 0) i0 = 0; w1 = 2.f / 3.f; }
}

// ---------- fused output, one y-triple per 768-thread block, scan-free.
// Map rows {clamp(d-1), d, clamp(d+1)} of AB1/AB2 loaded ONCE; group g
// (=row slot rr) builds its packed ry row; phase 2 = gather+affine+write.
// y=3d   : (1/3)row[d-1] + (2/3)row[d]
// y=3d+1 : row[d]
// y=3d+2 : (2/3)row[d] + (1/3)row[d+1]
__global__ __launch_bounds__(768) void k_final(
    const float* __restrict__ x, const float2* __restrict__ AB1,
    const float2* __restrict__ AB2, float* __restrict__ out) {
  __shared__ float2 sA[3][HL], sC[3][HL];
  __shared__ float4 ry[3][HL];
  int nb_ = blockIdx.x;  // n*256 + d
  int d = nb_ & 255, n = nb_ >> 8;
  int t = threadIdx.x;
  int rr = t >> 8, j = t & 255;  // rr = 0..2
  size_t mb = (size_t)n * SLICE;
  int rowi = d - 1 + rr; rowi = rowi < 0 ? 0 : (rowi > HL - 1 ? HL - 1 : rowi);
  sA[rr][j] = AB1[mb + (size_t)rowi * HL + j];
  sC[rr][j] = AB2[mb + (size_t)rowi * HL + j];
  __syncthreads();
  {
    // group rr computes the y=3d+rr map row (same mul/add order as upw path)
    float wy1 = (rr == 0) ? (2.f / 3.f) : ((rr == 2) ? (1.f / 3.f) : 0.f);
    float wy0 = 1.f - wy1;
    int s0 = (rr == 0) ? 0 : 1;   // iy0 slot
    int s1 = (rr == 2) ? 2 : 1;   // iy1 slot
    float2 a0 = sA[s0][j], a1 = sA[s1][j];
    float2 c0 = sC[s0][j], c1 = sC[s1][j];
    ry[rr][j] = make_float4(wy0 * a0.x + wy1 * a1.x, wy0 * a0.y + wy1 * a1.y,
                            wy0 * c0.x + wy1 * c1.x, wy0 * c0.y + wy1 * c1.y);
  }
  __syncthreads();
  if (j < 192) {
    int y = 3 * d + rr;
    float A1c[4], B1c[4], A2c[4], B2c[4];
#pragma unroll
    for (int e = 0; e < 4; ++e) {
      int q = 4 * j + e;
      int ix0, ix1;
      float wx1;
      upw(q, ix0, ix1, wx1);
      float wx0 = 1.f - wx1;
      float4 m0 = ry[rr][ix0], m1 = ry[rr][ix1];
      A1c[e] = wx0 * m0.x + wx1 * m1.x;
      B1c[e] = wx0 * m0.y + wx1 * m1.y;
      A2c[e] = wx0 * m0.z + wx1 * m1.z;
      B2c[e] = wx0 * m0.w + wx1 * m1.w;
    }
    size_t rowbase = ((size_t)(n * CCH) * HF + y) * HF + 4 * j;
#pragma unroll
    for (int c = 0; c < CCH; ++c) {
      const float4 xin = *(const float4*)(x + rowbase + (size_t)c * HF * HF);
      float4 o;
      o.x = A2c[0] * (A1c[0] * xin.x + B1c[0]) + B2c[0];
      o.y = A2c[1] * (A1c[1] * xin.y + B1c[1]) + B2c[1];
      o.z = A2c[2] * (A1c[2] * xin.z + B1c[2]) + B2c[2];
      o.w = A2c[3] * (A1c[3] * xin.w + B1c[3]) + B2c[3];
      *(float4*)(out + rowbase + (size_t)c * HF * HF) = o;
    }
  }
}

extern "C" void kernel_launch(void* const* d_in, const int* in_sizes, int n_in,
                              void* d_out, int out_size, void* d_ws, size_t ws_size,
                              hipStream_t stream) {
  const float* x = (const float*)d_in[0];
  float* out = (float*)d_out;
  const size_t S = (size_t)TOT_L;  // elements per packed (float2) array
  float2 *UV, *Spk, *Ppk, *AB1, *Rpk, *AB2, *Qpk;
  if (ws_size >= 12 * S * sizeof(float)) {
    float2* w = (float2*)d_ws;
    UV = w; Spk = UV + S; Ppk = Spk + S; AB1 = Ppk + S; Rpk = AB1 + S;
    AB2 = Rpk + S;
  } else {
    // Maps k_final reads (AB1, AB2) stay in ws (16 MB); transients live at
    // the head of d_out (each fully written before read, every call).
    AB1 = (float2*)d_ws; AB2 = AB1 + S;
    UV = (float2*)out; Spk = UV + S; Ppk = Spk + S; Rpk = Ppk + S;
  }
  Qpk = Spk;  // S dead after k2; k3 writes Q there, k4 reads

  k1<<<N_B * 64, 1024, 0, stream>>>(x, UV, Spk);
  k2<<<N_B * 64, 1024, 0, stream>>>(Spk, Ppk);
  k3<<<N_B * 64, 1024, 0, stream>>>(Ppk, UV, AB1, Qpk);
  k4<<<N_B * 64, 1024, 0, stream>>>(Qpk, Rpk);
  k5<<<N_B * 64, 1024, 0, stream>>>(Rpk, AB2);
  k_final<<<N_B * HL, 768, 0, stream>>>(x, AB1, AB2, out);
}

// Round 16
// 96.174 us; speedup vs baseline: 1.0742x; 1.0742x over previous
//
#include <hip/hip_runtime.h>

// ReceptiveFieldNorm, N=16 C=3 H=W=768, fp32. Two iterations (win 51 then 13
// at 256x256). All vertical boxes are horizontal shfl-scans in transposed
// orientation. 5 dispatches (minimal: 4 orientation flips). Best-measured
// configuration (96.2 us): direct strided loads in k1, 2-barrier
// double-buffered scans, wy1==0 fast path in k_final.

#define N_B 16
#define CCH 3
#define HF 768
#define HL 256
#define SLICE (HL * HL)
#define TOT_L (N_B * SLICE)
#define EPSV 1e-3f

__device__ __forceinline__ int cnt(int i, int P) {
  int hi = i + P; if (hi > HL - 1) hi = HL - 1;
  int lo = i - P; if (lo < 0) lo = 0;
  return hi - lo + 1;
}

// Dual inclusive prefix scan of a 256-wide row per group g into s[g][*].
// 2 syncthreads. Caller must pass a FRESH buffer pair (s,wt) per call
// (double-buffer) -- there is no entry guard.
__device__ __forceinline__ void scan2g(float a, float b, int g, int j,
    float2 (*s)[HL], float2 (*wt)[4]) {
  int lane = j & 63, w = j >> 6;
#pragma unroll
  for (int d = 1; d < 64; d <<= 1) {
    float ta = __shfl_up(a, (unsigned)d);
    float tb = __shfl_up(b, (unsigned)d);
    if (lane >= d) { a += ta; b += tb; }
  }
  if (lane == 63) wt[g][w] = make_float2(a, b);
  __syncthreads();
  float offa = 0.f, offb = 0.f;
  for (int ww = 0; ww < w; ++ww) { float2 t = wt[g][ww]; offa += t.x; offb += t.y; }
  s[g][j] = make_float2(a + offa, b + offb);
  __syncthreads();
}

// Zero-padded box result at position j from prefix array s[g].
template <int P>
__device__ __forceinline__ float2 boxr(const float2 (*s)[HL], int g, int j) {
  int hi = j + P; if (hi > HL - 1) hi = HL - 1;
  int lo = j - P - 1;
  float2 r = s[g][hi];
  if (lo >= 0) { float2 l = s[g][lo]; r.x -= l.x; r.y -= l.y; }
  return r;
}

// Transposed float2x4 write: thread tid (<256) writes dst[tid][col0..col0+3].
template <int P>
__device__ __forceinline__ void xpose_store(const float2 (*s)[HL], int tid,
    float2* __restrict__ dst, size_t nb, int col0) {
  if (tid < HL) {
    float2 r0 = boxr<P>(s, 0, tid);
    float2 r1 = boxr<P>(s, 1, tid);
    float2 r2 = boxr<P>(s, 2, tid);
    float2 r3 = boxr<P>(s, 3, tid);
    float4* d = (float4*)(dst + nb + (size_t)tid * HL + col0);
    d[0] = make_float4(r0.x, r0.y, r1.x, r1.y);
    d[1] = make_float4(r2.x, r2.y, r3.x, r3.y);
  }
}

// ---------- k1: subsample + channel stats -> UV [N]; H25 scan -> S [T]
__global__ __launch_bounds__(1024) void k1(const float* __restrict__ x,
    float2* __restrict__ UV, float2* __restrict__ Spk) {
  __shared__ float2 sA[4][HL];
  __shared__ float2 wtA[4][4];
  int b = blockIdx.x;
  int n = b >> 6;           // 64 blocks per image
  int ib = (b & 63) << 2;   // first of 4 subsample rows
  int tid = threadIdx.x;
  int g = tid >> 8, j = tid & 255;
  const float* xp = x + (size_t)n * CCH * HF * HF
                  + (size_t)(3 * (ib + g) + 1) * HF + (3 * j + 1);
  float c0 = xp[0], c1 = xp[HF * HF], c2 = xp[2 * HF * HF];
  float uu = (c0 + c1 + c2) * (1.f / 3.f);
  float vv = (c0 * c0 + c1 * c1 + c2 * c2) * (1.f / 3.f);
  size_t nb = (size_t)n * SLICE;
  UV[nb + (size_t)(ib + g) * HL + j] = make_float2(uu, vv);
  scan2g(uu, vv, g, j, sA, wtA);
  xpose_store<25>(sA, tid, Spk, nb, ib);  // S[col=j][row=ib+g]
}

// ---------- k2: [T] scan25 -> box(u,v) -> f -> scan25 -> P [N]
__global__ __launch_bounds__(1024) void k2(const float2* __restrict__ Spk,
    float2* __restrict__ Ppk) {
  __shared__ float2 sA[4][HL], sB[4][HL];
  __shared__ float2 wtA[4][4], wtB[4][4];
  int n = blockIdx.x >> 6, strip = blockIdx.x & 63;
  int tid = threadIdx.x, g = tid >> 8, j = tid & 255;
  int c = strip * 4 + g;  // image col (T-row)
  size_t nb = (size_t)n * SLICE;
  float2 sv = Spk[nb + (size_t)c * HL + j];
  scan2g(sv.x, sv.y, g, j, sA, wtA);      // V25 prefix
  float2 bu = boxr<25>(sA, g, j);         // full box25 at (row j, col c)
  float invM = 1.f / ((float)cnt(j, 25) * (float)cnt(c, 25));
  float xm = bu.x * invM, x2m = bu.y * invM;
  float var = x2m - xm * xm; if (var < 0.f) var = 0.f;
  float inv = 1.f / sqrtf(var + EPSV);
  scan2g(inv, -xm * inv, g, j, sB, wtB);  // V25 prefix of (a,b)
  xpose_store<25>(sB, tid, Ppk, nb, strip * 4);  // P[row=j][col=c]
}

// ---------- k3: [N] scan25 -> A1,B1; iter2 stats; H6 scan -> Q [T]
__global__ __launch_bounds__(1024) void k3(const float2* __restrict__ Ppk,
    const float2* __restrict__ UV, float2* __restrict__ AB1,
    float2* __restrict__ Qpk) {
  __shared__ float2 sA[4][HL], sB[4][HL];
  __shared__ float2 wtA[4][4], wtB[4][4];
  int n = blockIdx.x >> 6, strip = blockIdx.x & 63;
  int tid = threadIdx.x, g = tid >> 8, j = tid & 255;
  int i = strip * 4 + g;  // image row
  size_t nb = (size_t)n * SLICE;
  size_t idx = nb + (size_t)i * HL + j;
  float2 pv = Ppk[idx];
  scan2g(pv.x, pv.y, g, j, sA, wtA);      // H25 prefix of (a,b)
  float2 bb = boxr<25>(sA, g, j);
  float invM = 1.f / ((float)cnt(i, 25) * (float)cnt(j, 25));
  float Av = bb.x * invM, Bv = bb.y * invM;
  AB1[idx] = make_float2(Av, Bv);
  float2 uv = UV[idx];
  float u2 = Av * uv.x + Bv;
  float v2 = Av * Av * uv.y + 2.f * Av * Bv * uv.x + Bv * Bv;
  scan2g(u2, v2, g, j, sB, wtB);          // H6 prefix of (u2,v2)
  xpose_store<6>(sB, tid, Qpk, nb, strip * 4);  // Q[col=j][row=i]
}

// ---------- k4: [T] scan6 -> box6 -> f6 -> scan6 -> R [N]
__global__ __launch_bounds__(1024) void k4(const float2* __restrict__ Qpk,
    float2* __restrict__ Rpk) {
  __shared__ float2 sA[4][HL], sB[4][HL];
  __shared__ float2 wtA[4][4], wtB[4][4];
  int n = blockIdx.x >> 6, strip = blockIdx.x & 63;
  int tid = threadIdx.x, g = tid >> 8, j = tid & 255;
  int c = strip * 4 + g;  // image col
  size_t nb = (size_t)n * SLICE;
  float2 qv = Qpk[nb + (size_t)c * HL + j];
  scan2g(qv.x, qv.y, g, j, sA, wtA);      // V6 prefix
  float2 bu = boxr<6>(sA, g, j);          // full box6 at (row j, col c)
  float invM = 1.f / ((float)cnt(j, 6) * (float)cnt(c, 6));
  float xm = bu.x * invM, x2m = bu.y * invM;
  float var = x2m - xm * xm; if (var < 0.f) var = 0.f;
  float inv = 1.f / sqrtf(var + EPSV);
  scan2g(inv, -xm * inv, g, j, sB, wtB);  // V6 prefix of (a2,b2)
  xpose_store<6>(sB, tid, Rpk, nb, strip * 4);  // R[row=j][col=c]
}

// ---------- bilinear upsample weights for 256 -> 768 (period-3 pattern)
__device__ __forceinline__ void upw(int q, int& i0, int& i1, float& w1) {
  int d = q / 3;
  int r = q - 3 * d;
  if (r == 1) { i0 = d; i1 = d; w1 = 0.f; }
  else if (r == 2) { i0 = d; i1 = d + 1; if (i1 > HL - 1) i1 = HL - 1; w1 = 1.f / 3.f; }
  else { i1 = d; i0 = d - 1; if (i0 < 0) i0 = 0; w1 = 2.f / 3.f; }
}

// ---------- fused output: H6-scan of R rows (A2,B2) + upsample + affine
__global__ __launch_bounds__(256) void k_final(
    const float* __restrict__ x, const float2* __restrict__ AB1,
    const float2* __restrict__ Rpk, float* __restrict__ out) {
  __shared__ float2 ry01[HL], ry23[HL];
  __shared__ float2 sA[1][HL], sB[1][HL];
  __shared__ float2 wtA[1][4], wtB[1][4];
  int nb_ = blockIdx.x;  // n*768 + y
  int y = nb_ % HF;
  int n = nb_ / HF;
  int t = threadIdx.x;  // 0..255
  int iy0, iy1;
  float wy1;
  upw(y, iy0, iy1, wy1);
  float wy0 = 1.f - wy1;
  size_t mb = (size_t)n * SLICE;
  // maps 0,1: bilinear-y of A1,B1
  float2 a0 = AB1[mb + (size_t)iy0 * HL + t];
  float2 a1 = AB1[mb + (size_t)iy1 * HL + t];
  ry01[t] = make_float2(wy0 * a0.x + wy1 * a1.x, wy0 * a0.y + wy1 * a1.y);
  // maps 2,3: H6-scan R rows iy0/iy1 -> A2,B2 rows, then bilinear-y
  float cj6 = (float)cnt(t, 6);
  float2 r0v = Rpk[mb + (size_t)iy0 * HL + t];
  scan2g(r0v.x, r0v.y, 0, t, sA, wtA);
  float2 b0 = boxr<6>(sA, 0, t);
  float inv0 = 1.f / ((float)cnt(iy0, 6) * cj6);
  float A20 = b0.x * inv0, B20 = b0.y * inv0;
  if (wy1 == 0.f) {  // exact-sample rows (y%3==1): single map row suffices
    ry23[t] = make_float2(A20, B20);
  } else {
    float2 r1v = Rpk[mb + (size_t)iy1 * HL + t];
    scan2g(r1v.x, r1v.y, 0, t, sB, wtB);
    float2 b1 = boxr<6>(sB, 0, t);
    float inv1 = 1.f / ((float)cnt(iy1, 6) * cj6);
    ry23[t] = make_float2(wy0 * A20 + wy1 * b1.x * inv1,
                          wy0 * B20 + wy1 * b1.y * inv1);
  }
  __syncthreads();
  if (t < 192) {
    float A1c[4], B1c[4], A2c[4], B2c[4];
#pragma unroll
    for (int e = 0; e < 4; ++e) {
      int q = 4 * t + e;
      int ix0, ix1;
      float wx1;
      upw(q, ix0, ix1, wx1);
      float wx0 = 1.f - wx1;
      float2 m0 = ry01[ix0], m1 = ry01[ix1];
      float2 m2 = ry23[ix0], m3 = ry23[ix1];
      A1c[e] = wx0 * m0.x + wx1 * m1.x;
      B1c[e] = wx0 * m0.y + wx1 * m1.y;
      A2c[e] = wx0 * m2.x + wx1 * m3.x;
      B2c[e] = wx0 * m2.y + wx1 * m3.y;
    }
    size_t rowbase = ((size_t)(n * CCH) * HF + y) * HF + 4 * t;
#pragma unroll
    for (int c = 0; c < CCH; ++c) {
      const float4 xin = *(const float4*)(x + rowbase + (size_t)c * HF * HF);
      float4 o;
      o.x = A2c[0] * (A1c[0] * xin.x + B1c[0]) + B2c[0];
      o.y = A2c[1] * (A1c[1] * xin.y + B1c[1]) + B2c[1];
      o.z = A2c[2] * (A1c[2] * xin.z + B1c[2]) + B2c[2];
      o.w = A2c[3] * (A1c[3] * xin.w + B1c[3]) + B2c[3];
      *(float4*)(out + rowbase + (size_t)c * HF * HF) = o;
    }
  }
}

extern "C" void kernel_launch(void* const* d_in, const int* in_sizes, int n_in,
                              void* d_out, int out_size, void* d_ws, size_t ws_size,
                              hipStream_t stream) {
  const float* x = (const float*)d_in[0];
  float* out = (float*)d_out;
  const size_t S = (size_t)TOT_L;  // elements per packed (float2) array
  float2 *UV, *Spk, *Ppk, *AB1, *Rpk, *Qpk;
  if (ws_size >= 10 * S * sizeof(float)) {
    float2* w = (float2*)d_ws;
    UV = w; Spk = UV + S; Ppk = Spk + S; AB1 = Ppk + S; Rpk = AB1 + S;
  } else {
    // Buffers k_final reads stay in ws (16 MB); transients live at the head
    // of d_out (each fully written before read, every call).
    AB1 = (float2*)d_ws; Rpk = AB1 + S;
    UV = (float2*)out; Spk = UV + S; Ppk = Spk + S;
  }
  Qpk = Spk;  // S dead after k2; k3 writes Q there, k4 reads

  k1<<<N_B * 64, 1024, 0, stream>>>(x, UV, Spk);
  k2<<<N_B * 64, 1024, 0, stream>>>(Spk, Ppk);
  k3<<<N_B * 64, 1024, 0, stream>>>(Ppk, UV, AB1, Qpk);
  k4<<<N_B * 64, 1024, 0, stream>>>(Qpk, Rpk);
  k_final<<<N_B * HF, 256, 0, stream>>>(x, AB1, Rpk, out);
}